// Round 1
// baseline (1175.544 us; speedup 1.0000x reference)
//
#include <hip/hip_runtime.h>
#include <math.h>

#define N_NODES 50000
#define N_EDGES 500000
#define EP (N_EDGES + N_NODES)   // edges + self loops = 550000
#define IN_F 128
#define HID 64
#define HEADS 4
#define ZD (HEADS * HID)         // 256
#define G_B 16
#define OUT_F 326000
#define NEG 0.2f
#define SCAN_BLK 256
#define NBLK_SCAN ((N_NODES + SCAN_BLK - 1) / SCAN_BLK)   // 196

// ---------------- init: counts=1 (self loop), cursor=0, pool=0 ----------------
__global__ void k_init(int* counts, int* cursor, float* pool, float* pool_cnt) {
    int i = blockIdx.x * 256 + threadIdx.x;
    if (i < N_NODES) { counts[i] = 1; cursor[i] = 0; }
    if (i < G_B * HID) pool[i] = 0.f;
    if (i < G_B) pool_cnt[i] = 0.f;
}

// ---------------- count real edges per dst ----------------
__global__ void k_count(const int* __restrict__ ei, int* __restrict__ counts) {
    int i = blockIdx.x * 256 + threadIdx.x;
    if (i < N_EDGES) atomicAdd(&counts[ei[N_EDGES + i]], 1);
}

// ---------------- scan step 1: per-block inclusive scan ----------------
__global__ void k_scan1(const int* __restrict__ counts, int* __restrict__ tmp,
                        int* __restrict__ partial) {
    __shared__ int s[SCAN_BLK];
    int t = threadIdx.x;
    int i = blockIdx.x * SCAN_BLK + t;
    int v = (i < N_NODES) ? counts[i] : 0;
    s[t] = v;
    __syncthreads();
    for (int off = 1; off < SCAN_BLK; off <<= 1) {
        int a = (t >= off) ? s[t - off] : 0;
        __syncthreads();
        s[t] += a;
        __syncthreads();
    }
    if (i < N_NODES) tmp[i] = s[t];
    if (t == SCAN_BLK - 1) partial[blockIdx.x] = s[t];
}

// ---------------- scan step 2: exclusive scan of block partials ----------------
__global__ void k_scan2(int* partial) {
    __shared__ int s[SCAN_BLK];
    int t = threadIdx.x;
    int v = (t < NBLK_SCAN) ? partial[t] : 0;
    s[t] = v;
    __syncthreads();
    for (int off = 1; off < SCAN_BLK; off <<= 1) {
        int a = (t >= off) ? s[t - off] : 0;
        __syncthreads();
        s[t] += a;
        __syncthreads();
    }
    if (t < NBLK_SCAN) partial[t] = s[t] - v;   // exclusive
}

// ---------------- scan step 3: global exclusive offsets ----------------
__global__ void k_scan3(const int* __restrict__ tmp, const int* __restrict__ counts,
                        const int* __restrict__ partial, int* __restrict__ offsets) {
    int i = blockIdx.x * 256 + threadIdx.x;
    if (i < N_NODES) offsets[i] = tmp[i] - counts[i] + partial[i >> 8];
    if (i == 0) offsets[N_NODES] = EP;
}

// ---------------- fill CSR: edge_src grouped by dst ----------------
__global__ void k_fill(const int* __restrict__ ei, const int* __restrict__ offsets,
                       int* __restrict__ cursor, int* __restrict__ edge_src) {
    int i = blockIdx.x * 256 + threadIdx.x;
    if (i >= EP) return;
    int s, d;
    if (i < N_EDGES) { s = ei[i]; d = ei[N_EDGES + i]; }
    else             { s = d = i - N_EDGES; }
    int pos = offsets[d] + atomicAdd(&cursor[d], 1);
    edge_src[pos] = s;
}

// ---------------- node embedding: h = x @ W_emb + b_emb ----------------
__global__ void k_emb(const float* __restrict__ x, const float* __restrict__ W,
                      const float* __restrict__ b, float* __restrict__ h) {
    __shared__ float xs[IN_F];
    int n = blockIdx.x;
    int f = threadIdx.x;           // 64 threads = 1 wave
    xs[f]      = x[(size_t)n * IN_F + f];
    xs[f + 64] = x[(size_t)n * IN_F + 64 + f];
    __syncthreads();
    float acc = b[f];
    #pragma unroll 8
    for (int k = 0; k < IN_F; k++) acc += xs[k] * W[k * HID + f];
    h[n * HID + f] = acc;
}

// ---------------- per-layer: z = h @ W, al_s/al_d attention logits ----------------
__global__ void k_z(const float* __restrict__ h, const float* __restrict__ W,
                    const float* __restrict__ a_src, const float* __restrict__ a_dst,
                    float* __restrict__ z, float* __restrict__ al_s,
                    float* __restrict__ al_d) {
    __shared__ float hs[HID];
    int n = blockIdx.x;
    int t = threadIdx.x;           // 256 threads: t = head*64 + feat
    if (t < HID) hs[t] = h[n * HID + t];
    __syncthreads();
    float acc = 0.f;
    #pragma unroll 8
    for (int k = 0; k < HID; k++) acc += hs[k] * W[k * ZD + t];
    z[(size_t)n * ZD + t] = acc;
    // attention logit partials; att layout [HEADS,HID] flattened == t
    float ps = acc * a_src[t];
    float pd = acc * a_dst[t];
    for (int off = 32; off > 0; off >>= 1) {
        ps += __shfl_down(ps, off);
        pd += __shfl_down(pd, off);
    }
    if ((t & 63) == 0) {
        int hd = t >> 6;
        al_s[n * HEADS + hd] = ps;
        al_d[n * HEADS + hd] = pd;
    }
}

__device__ __forceinline__ float lrelu(float v) { return v > 0.f ? v : NEG * v; }

// ---------------- fused segment softmax + weighted aggregate + head mean ----------------
__global__ void k_agg(const int* __restrict__ offsets, const int* __restrict__ edge_src,
                      const float* __restrict__ al_s, const float* __restrict__ al_d,
                      const float* __restrict__ z, const float* __restrict__ b,
                      float* __restrict__ h) {
    __shared__ float accs[HEADS][HID];
    int d  = blockIdx.x;
    int t  = threadIdx.x;
    int hd = t >> 6;               // wave id == head
    int f  = t & 63;               // lane == feature
    int start = offsets[d];
    int end   = offsets[d + 1];
    float al_dd = al_d[d * HEADS + hd];

    // per-lane online softmax over incident edges
    float m = -INFINITY, ssum = 0.f;
    for (int i = start + f; i < end; i += 64) {
        int s = edge_src[i];
        float ev = lrelu(al_s[s * HEADS + hd] + al_dd);
        float nm = fmaxf(m, ev);
        ssum = ssum * expf(m - nm) + expf(ev - nm);
        m = nm;
    }
    // combine lanes: global max
    float M = m;
    for (int off = 32; off > 0; off >>= 1) M = fmaxf(M, __shfl_down(M, off));
    M = __shfl(M, 0);
    float contrib = ssum * expf(m - M);   // -inf lanes give 0*0 = 0
    float S = contrib;
    for (int off = 32; off > 0; off >>= 1) S += __shfl_down(S, off);
    S = __shfl(S, 0);
    float inv = 1.f / (S + 1e-16f);

    // weighted gather of z rows
    float acc = 0.f;
    for (int i = start; i < end; i++) {
        int s = edge_src[i];                       // uniform -> broadcast
        float ev = lrelu(al_s[s * HEADS + hd] + al_dd);
        float alpha = expf(ev - M) * inv;
        acc += z[(size_t)s * ZD + hd * HID + f] * alpha;
    }
    accs[hd][f] = acc;
    __syncthreads();
    if (t < HID) {
        float r = (accs[0][t] + accs[1][t] + accs[2][t] + accs[3][t]) * 0.25f + b[t];
        h[d * HID + t] = fmaxf(r, 0.f);
    }
}

// ---------------- global mean pool (batch is sorted) ----------------
__global__ void k_pool(const float* __restrict__ h, const int* __restrict__ batch,
                       float* __restrict__ pool, float* __restrict__ pool_cnt) {
    int f = threadIdx.x;           // 64 threads
    int n0 = blockIdx.x * 256;
    int n1 = n0 + 256;
    if (n1 > N_NODES) n1 = N_NODES;
    if (n0 >= n1) return;
    int curg = batch[n0];
    float acc = 0.f;
    int cnt = 0;
    for (int n = n0; n < n1; n++) {
        int g = batch[n];
        if (g != curg) {
            atomicAdd(&pool[curg * HID + f], acc);
            if (f == 0) atomicAdd(&pool_cnt[curg], (float)cnt);
            acc = 0.f; cnt = 0; curg = g;
        }
        acc += h[n * HID + f];
        cnt++;
    }
    atomicAdd(&pool[curg * HID + f], acc);
    if (f == 0) atomicAdd(&pool_cnt[curg], (float)cnt);
}

// ---------------- final FC: out = hg @ W_fc + b_fc ----------------
__global__ void k_fc(const float* __restrict__ pool, const float* __restrict__ pool_cnt,
                     const float* __restrict__ W_fc, const float* __restrict__ b_fc,
                     float* __restrict__ out) {
    __shared__ float hg[G_B * HID];
    int t = threadIdx.x;
    for (int i = t; i < G_B * HID; i += 256)
        hg[i] = pool[i] / fmaxf(pool_cnt[i / HID], 1.f);
    __syncthreads();
    int o = blockIdx.x * 256 + t;
    if (o >= OUT_F) return;
    float acc[G_B];
    float bo = b_fc[o];
    #pragma unroll
    for (int g = 0; g < G_B; g++) acc[g] = bo;
    for (int k = 0; k < HID; k++) {
        float w = W_fc[(size_t)k * OUT_F + o];
        #pragma unroll
        for (int g = 0; g < G_B; g++) acc[g] += hg[g * HID + k] * w;
    }
    #pragma unroll
    for (int g = 0; g < G_B; g++) out[(size_t)g * OUT_F + o] = acc[g];
}

extern "C" void kernel_launch(void* const* d_in, const int* in_sizes, int n_in,
                              void* d_out, int out_size, void* d_ws, size_t ws_size,
                              hipStream_t stream) {
    const float* x       = (const float*)d_in[0];
    const int*   ei      = (const int*)d_in[1];
    // d_in[2] edge_attr: unused by the reference forward
    const int*   batch   = (const int*)d_in[3];
    const float* W_emb   = (const float*)d_in[4];
    const float* b_emb   = (const float*)d_in[5];
    const float* W_gat   = (const float*)d_in[6];
    const float* att_src = (const float*)d_in[7];
    const float* att_dst = (const float*)d_in[8];
    const float* b_gat   = (const float*)d_in[9];
    const float* W_fc    = (const float*)d_in[10];
    const float* b_fc    = (const float*)d_in[11];
    float* out = (float*)d_out;

    char* p = (char*)d_ws;
    auto alloc = [&](size_t bytes) -> void* {
        void* r = (void*)p;
        p += (bytes + 255) & ~(size_t)255;
        return r;
    };
    float* h        = (float*)alloc((size_t)N_NODES * HID * 4);
    float* z        = (float*)alloc((size_t)N_NODES * ZD * 4);
    float* al_s     = (float*)alloc((size_t)N_NODES * HEADS * 4);
    float* al_d     = (float*)alloc((size_t)N_NODES * HEADS * 4);
    int*   counts   = (int*)alloc((size_t)N_NODES * 4);
    int*   offsets  = (int*)alloc((size_t)(N_NODES + 1) * 4);
    int*   cursor   = (int*)alloc((size_t)N_NODES * 4);
    int*   tmp      = (int*)alloc((size_t)N_NODES * 4);
    int*   partial  = (int*)alloc((size_t)SCAN_BLK * 4);
    int*   edge_src = (int*)alloc((size_t)EP * 4);
    float* pool     = (float*)alloc((size_t)G_B * HID * 4);
    float* pool_cnt = (float*)alloc((size_t)G_B * 4);

    // CSR build (once per launch; reused by all 3 layers)
    k_init <<<NBLK_SCAN, 256, 0, stream>>>(counts, cursor, pool, pool_cnt);
    k_count<<<(N_EDGES + 255) / 256, 256, 0, stream>>>(ei, counts);
    k_scan1<<<NBLK_SCAN, SCAN_BLK, 0, stream>>>(counts, tmp, partial);
    k_scan2<<<1, SCAN_BLK, 0, stream>>>(partial);
    k_scan3<<<NBLK_SCAN, 256, 0, stream>>>(tmp, counts, partial, offsets);
    k_fill <<<(EP + 255) / 256, 256, 0, stream>>>(ei, offsets, cursor, edge_src);

    // node embedding
    k_emb<<<N_NODES, 64, 0, stream>>>(x, W_emb, b_emb, h);

    // 3 GAT layers
    for (int l = 0; l < 3; l++) {
        k_z  <<<N_NODES, 256, 0, stream>>>(h, W_gat + (size_t)l * HID * ZD,
                                           att_src + (size_t)l * HEADS * HID,
                                           att_dst + (size_t)l * HEADS * HID,
                                           z, al_s, al_d);
        k_agg<<<N_NODES, 256, 0, stream>>>(offsets, edge_src, al_s, al_d, z,
                                           b_gat + (size_t)l * HID, h);
    }

    // pooling + FC
    k_pool<<<NBLK_SCAN, 64, 0, stream>>>(h, batch, pool, pool_cnt);
    k_fc  <<<(OUT_F + 255) / 256, 256, 0, stream>>>(pool, pool_cnt, W_fc, b_fc, out);
}

// Round 2
// 791.561 us; speedup vs baseline: 1.4851x; 1.4851x over previous
//
#include <hip/hip_runtime.h>
#include <math.h>

#define N_NODES 50000
#define N_EDGES 500000
#define EP (N_EDGES + N_NODES)   // edges + self loops = 550000
#define IN_F 128
#define HID 64
#define HEADS 4
#define ZD (HEADS * HID)         // 256
#define G_B 16
#define OUT_F 326000
#define NEG 0.2f
#define SCAN_BLK 256
#define NBLK_SCAN ((N_NODES + SCAN_BLK - 1) / SCAN_BLK)   // 196
#define CAP 64                   // LDS-stash cap per dst (deg > CAP -> slow path)
#define EVS 72                   // per-head LDS stride (72 -> 2-way-free bank pattern)

// ---------------- init: counts=1 (self loop), cursor=0, pool=0 ----------------
__global__ void k_init(int* counts, int* cursor, float* pool, float* pool_cnt) {
    int i = blockIdx.x * 256 + threadIdx.x;
    if (i < N_NODES) { counts[i] = 1; cursor[i] = 0; }
    if (i < G_B * HID) pool[i] = 0.f;
    if (i < G_B) pool_cnt[i] = 0.f;
}

__global__ void k_count(const int* __restrict__ ei, int* __restrict__ counts) {
    int i = blockIdx.x * 256 + threadIdx.x;
    if (i < N_EDGES) atomicAdd(&counts[ei[N_EDGES + i]], 1);
}

__global__ void k_scan1(const int* __restrict__ counts, int* __restrict__ tmp,
                        int* __restrict__ partial) {
    __shared__ int s[SCAN_BLK];
    int t = threadIdx.x;
    int i = blockIdx.x * SCAN_BLK + t;
    int v = (i < N_NODES) ? counts[i] : 0;
    s[t] = v;
    __syncthreads();
    for (int off = 1; off < SCAN_BLK; off <<= 1) {
        int a = (t >= off) ? s[t - off] : 0;
        __syncthreads();
        s[t] += a;
        __syncthreads();
    }
    if (i < N_NODES) tmp[i] = s[t];
    if (t == SCAN_BLK - 1) partial[blockIdx.x] = s[t];
}

__global__ void k_scan2(int* partial) {
    __shared__ int s[SCAN_BLK];
    int t = threadIdx.x;
    int v = (t < NBLK_SCAN) ? partial[t] : 0;
    s[t] = v;
    __syncthreads();
    for (int off = 1; off < SCAN_BLK; off <<= 1) {
        int a = (t >= off) ? s[t - off] : 0;
        __syncthreads();
        s[t] += a;
        __syncthreads();
    }
    if (t < NBLK_SCAN) partial[t] = s[t] - v;   // exclusive
}

__global__ void k_scan3(const int* __restrict__ tmp, const int* __restrict__ counts,
                        const int* __restrict__ partial, int* __restrict__ offsets) {
    int i = blockIdx.x * 256 + threadIdx.x;
    if (i < N_NODES) offsets[i] = tmp[i] - counts[i] + partial[i >> 8];
    if (i == 0) offsets[N_NODES] = EP;
}

__global__ void k_fill(const int* __restrict__ ei, const int* __restrict__ offsets,
                       int* __restrict__ cursor, int* __restrict__ edge_src) {
    int i = blockIdx.x * 256 + threadIdx.x;
    if (i >= EP) return;
    int s, d;
    if (i < N_EDGES) { s = ei[i]; d = ei[N_EDGES + i]; }
    else             { s = d = i - N_EDGES; }
    int pos = offsets[d] + atomicAdd(&cursor[d], 1);
    edge_src[pos] = s;
}

// ---------------- node embedding: 1 wave = 8 nodes; x via uniform (scalar) loads ----
#define NPE 8
__global__ void k_emb(const float* __restrict__ x, const float* __restrict__ W,
                      const float* __restrict__ b, float* __restrict__ h) {
    int l = threadIdx.x;                         // 64 threads = 1 wave
    const float* xp = x + (size_t)blockIdx.x * NPE * IN_F;   // uniform base
    float bv = b[l];
    float acc[NPE];
    #pragma unroll
    for (int n = 0; n < NPE; n++) acc[n] = bv;
    for (int k = 0; k < IN_F; k++) {
        float wv = W[k * HID + l];
        #pragma unroll
        for (int n = 0; n < NPE; n++) acc[n] += xp[n * IN_F + k] * wv;
    }
    size_t nb = (size_t)blockIdx.x * NPE;
    #pragma unroll
    for (int n = 0; n < NPE; n++) h[(nb + n) * HID + l] = acc[n];
}

// ---------------- z = h @ W: 16 nodes/block, h via uniform loads --------------
#define NPZ 16
__global__ void k_z(const float* __restrict__ h, const float* __restrict__ W,
                    float* __restrict__ z) {
    int t = threadIdx.x;                         // 256 threads: output column
    const float* hp = h + (size_t)blockIdx.x * NPZ * HID;    // uniform base
    float acc[NPZ];
    #pragma unroll
    for (int n = 0; n < NPZ; n++) acc[n] = 0.f;
    for (int k = 0; k < HID; k++) {
        float wv = W[k * ZD + t];
        #pragma unroll
        for (int n = 0; n < NPZ; n++) acc[n] += hp[n * HID + k] * wv;
    }
    size_t nb = (size_t)blockIdx.x * NPZ;
    #pragma unroll
    for (int n = 0; n < NPZ; n++) z[(nb + n) * ZD + t] = acc[n];
}

// ---------------- attention logits: 1 wave per node, float4 row read ----------
__global__ void k_att(const float* __restrict__ z, const float* __restrict__ a_src,
                      const float* __restrict__ a_dst, float* __restrict__ al_s,
                      float* __restrict__ al_d) {
    int t = threadIdx.x;
    int w = t >> 6, l = t & 63;
    int n = blockIdx.x * 4 + w;
    float4 zr = *(const float4*)&z[(size_t)n * ZD + l * 4];
    float4 as = *(const float4*)&a_src[l * 4];
    float4 ad = *(const float4*)&a_dst[l * 4];
    float ps = zr.x * as.x + zr.y * as.y + zr.z * as.z + zr.w * as.w;
    float pd = zr.x * ad.x + zr.y * ad.y + zr.z * ad.z + zr.w * ad.w;
    for (int o = 8; o > 0; o >>= 1) {
        ps += __shfl_xor(ps, o);
        pd += __shfl_xor(pd, o);
    }
    if ((l & 15) == 0) {
        int hd = l >> 4;
        al_s[n * HEADS + hd] = ps;
        al_d[n * HEADS + hd] = pd;
    }
}

__device__ __forceinline__ float lrelu(float v) { return v > 0.f ? v : NEG * v; }

// ---------------- fused softmax + aggregate: ONE WAVE PER DST ----------------
// lane l: head hd = l>>4, feature quad f4 = (l&15)*4. One float4 load per lane
// covers the full 256-float z row per edge. src idx + ev stashed in LDS.
__global__ void k_agg(const int* __restrict__ offsets, const int* __restrict__ edge_src,
                      const float* __restrict__ al_s, const float* __restrict__ al_d,
                      const float* __restrict__ z, const float* __restrict__ b,
                      float* __restrict__ h) {
    __shared__ float evb[4][HEADS * EVS];   // per wave: per-head alpha stash
    __shared__ int   sb[4][CAP];            // per wave: src idx stash
    int t  = threadIdx.x;
    int w  = t >> 6;                        // wave in block
    int l  = t & 63;
    int hd = l >> 4;                        // head
    int j  = l & 15;                        // lane within head group
    int d  = blockIdx.x * 4 + w;            // dst node (50000 % 4 == 0)

    int start = __builtin_amdgcn_readfirstlane(offsets[d]);
    int end   = __builtin_amdgcn_readfirstlane(offsets[d + 1]);
    int deg   = end - start;
    float al_dd = al_d[d * HEADS + hd];

    // phase 1: per-lane online softmax over strided edges; stash src + ev
    float m = -INFINITY, ssum = 0.f;
    for (int i = start + j; i < end; i += 16) {
        int s = edge_src[i];
        int slot = i - start;
        if (hd == 0 && slot < CAP) sb[w][slot] = s;
        float ev = lrelu(al_s[s * HEADS + hd] + al_dd);
        if (slot < CAP) evb[w][hd * EVS + slot] = ev;
        float nm = fmaxf(m, ev);
        ssum = ssum * __expf(m - nm) + __expf(ev - nm);
        m = nm;
    }
    // group (16-lane) reductions
    float M = m;
    for (int o = 8; o > 0; o >>= 1) M = fmaxf(M, __shfl_xor(M, o));
    float S = ssum * __expf(m - M);
    for (int o = 8; o > 0; o >>= 1) S += __shfl_xor(S, o);
    float inv = 1.f / (S + 1e-16f);
    // convert stashed ev -> alpha
    int stop = deg < CAP ? deg : CAP;
    for (int slot = j; slot < stop; slot += 16)
        evb[w][hd * EVS + slot] = __expf(evb[w][hd * EVS + slot] - M) * inv;

    // phase 2: weighted float4 gather of full z rows
    float4 acc = {0.f, 0.f, 0.f, 0.f};
    for (int i = start; i < end; i++) {
        int slot = i - start;
        int s; float alpha;
        if (slot < CAP) {
            s = sb[w][slot];                              // LDS broadcast
            alpha = evb[w][hd * EVS + slot];
        } else {                                          // astronomically rare
            s = __builtin_amdgcn_readfirstlane(edge_src[i]);
            float ev = lrelu(al_s[s * HEADS + hd] + al_dd);
            alpha = __expf(ev - M) * inv;
        }
        float4 zr = *(const float4*)&z[(size_t)s * ZD + l * 4];
        acc.x += alpha * zr.x;
        acc.y += alpha * zr.y;
        acc.z += alpha * zr.z;
        acc.w += alpha * zr.w;
    }
    // head mean: sum across the 4 head groups (lanes l, l^16, l^32 hold same feats)
    acc.x += __shfl_xor(acc.x, 16); acc.y += __shfl_xor(acc.y, 16);
    acc.z += __shfl_xor(acc.z, 16); acc.w += __shfl_xor(acc.w, 16);
    acc.x += __shfl_xor(acc.x, 32); acc.y += __shfl_xor(acc.y, 32);
    acc.z += __shfl_xor(acc.z, 32); acc.w += __shfl_xor(acc.w, 32);
    if (l < 16) {
        float4 bv = *(const float4*)&b[l * 4];
        float4 r;
        r.x = fmaxf(acc.x * 0.25f + bv.x, 0.f);
        r.y = fmaxf(acc.y * 0.25f + bv.y, 0.f);
        r.z = fmaxf(acc.z * 0.25f + bv.z, 0.f);
        r.w = fmaxf(acc.w * 0.25f + bv.w, 0.f);
        *(float4*)&h[(size_t)d * HID + l * 4] = r;
    }
}

// ---------------- global mean pool (batch is sorted) ----------------
__global__ void k_pool(const float* __restrict__ h, const int* __restrict__ batch,
                       float* __restrict__ pool, float* __restrict__ pool_cnt) {
    int f = threadIdx.x;           // 64 threads
    int n0 = blockIdx.x * 256;
    int n1 = n0 + 256;
    if (n1 > N_NODES) n1 = N_NODES;
    if (n0 >= n1) return;
    int curg = batch[n0];
    float acc = 0.f;
    int cnt = 0;
    for (int n = n0; n < n1; n++) {
        int g = batch[n];
        if (g != curg) {
            atomicAdd(&pool[curg * HID + f], acc);
            if (f == 0) atomicAdd(&pool_cnt[curg], (float)cnt);
            acc = 0.f; cnt = 0; curg = g;
        }
        acc += h[n * HID + f];
        cnt++;
    }
    atomicAdd(&pool[curg * HID + f], acc);
    if (f == 0) atomicAdd(&pool_cnt[curg], (float)cnt);
}

// ---------------- final FC: out = hg @ W_fc + b_fc ----------------
__global__ void k_fc(const float* __restrict__ pool, const float* __restrict__ pool_cnt,
                     const float* __restrict__ W_fc, const float* __restrict__ b_fc,
                     float* __restrict__ out) {
    __shared__ float hg[G_B * HID];
    int t = threadIdx.x;
    for (int i = t; i < G_B * HID; i += 256)
        hg[i] = pool[i] / fmaxf(pool_cnt[i / HID], 1.f);
    __syncthreads();
    int o = blockIdx.x * 256 + t;
    if (o >= OUT_F) return;
    float acc[G_B];
    float bo = b_fc[o];
    #pragma unroll
    for (int g = 0; g < G_B; g++) acc[g] = bo;
    for (int k = 0; k < HID; k++) {
        float w = W_fc[(size_t)k * OUT_F + o];
        #pragma unroll
        for (int g = 0; g < G_B; g++) acc[g] += hg[g * HID + k] * w;
    }
    #pragma unroll
    for (int g = 0; g < G_B; g++) out[(size_t)g * OUT_F + o] = acc[g];
}

extern "C" void kernel_launch(void* const* d_in, const int* in_sizes, int n_in,
                              void* d_out, int out_size, void* d_ws, size_t ws_size,
                              hipStream_t stream) {
    const float* x       = (const float*)d_in[0];
    const int*   ei      = (const int*)d_in[1];
    // d_in[2] edge_attr: unused by the reference forward
    const int*   batch   = (const int*)d_in[3];
    const float* W_emb   = (const float*)d_in[4];
    const float* b_emb   = (const float*)d_in[5];
    const float* W_gat   = (const float*)d_in[6];
    const float* att_src = (const float*)d_in[7];
    const float* att_dst = (const float*)d_in[8];
    const float* b_gat   = (const float*)d_in[9];
    const float* W_fc    = (const float*)d_in[10];
    const float* b_fc    = (const float*)d_in[11];
    float* out = (float*)d_out;

    char* p = (char*)d_ws;
    auto alloc = [&](size_t bytes) -> void* {
        void* r = (void*)p;
        p += (bytes + 255) & ~(size_t)255;
        return r;
    };
    float* h        = (float*)alloc((size_t)N_NODES * HID * 4);
    float* z        = (float*)alloc((size_t)N_NODES * ZD * 4);
    float* al_s     = (float*)alloc((size_t)N_NODES * HEADS * 4);
    float* al_d     = (float*)alloc((size_t)N_NODES * HEADS * 4);
    int*   counts   = (int*)alloc((size_t)N_NODES * 4);
    int*   offsets  = (int*)alloc((size_t)(N_NODES + 1) * 4);
    int*   cursor   = (int*)alloc((size_t)N_NODES * 4);
    int*   tmp      = (int*)alloc((size_t)N_NODES * 4);
    int*   partial  = (int*)alloc((size_t)SCAN_BLK * 4);
    int*   edge_src = (int*)alloc((size_t)EP * 4);
    float* pool     = (float*)alloc((size_t)G_B * HID * 4);
    float* pool_cnt = (float*)alloc((size_t)G_B * 4);

    // CSR build (once per launch; reused by all 3 layers)
    k_init <<<NBLK_SCAN, 256, 0, stream>>>(counts, cursor, pool, pool_cnt);
    k_count<<<(N_EDGES + 255) / 256, 256, 0, stream>>>(ei, counts);
    k_scan1<<<NBLK_SCAN, SCAN_BLK, 0, stream>>>(counts, tmp, partial);
    k_scan2<<<1, SCAN_BLK, 0, stream>>>(partial);
    k_scan3<<<NBLK_SCAN, 256, 0, stream>>>(tmp, counts, partial, offsets);
    k_fill <<<(EP + 255) / 256, 256, 0, stream>>>(ei, offsets, cursor, edge_src);

    // node embedding
    k_emb<<<N_NODES / NPE, 64, 0, stream>>>(x, W_emb, b_emb, h);

    // 3 GAT layers
    for (int l = 0; l < 3; l++) {
        k_z  <<<N_NODES / NPZ, 256, 0, stream>>>(h, W_gat + (size_t)l * HID * ZD, z);
        k_att<<<N_NODES / 4, 256, 0, stream>>>(z,
                                               att_src + (size_t)l * HEADS * HID,
                                               att_dst + (size_t)l * HEADS * HID,
                                               al_s, al_d);
        k_agg<<<N_NODES / 4, 256, 0, stream>>>(offsets, edge_src, al_s, al_d, z,
                                               b_gat + (size_t)l * HID, h);
    }

    // pooling + FC
    k_pool<<<NBLK_SCAN, 64, 0, stream>>>(h, batch, pool, pool_cnt);
    k_fc  <<<(OUT_F + 255) / 256, 256, 0, stream>>>(pool, pool_cnt, W_fc, b_fc, out);
}